// Round 2
// 243.550 us; speedup vs baseline: 1.0012x; 1.0012x over previous
//
#include <hip/hip_runtime.h>
#include <math.h>

#define BATCH 16
#define NTOK 1024
#define HEADS 8
#define DHEAD 64
#define INNER 512
#define QKV_COLS 1536
// 0.125 * log2(e): p = exp2(qk*SCALE_L2E + bias*log2e)
#define SCALE_L2E 0.1803368801111244f
#define LOG2E 1.4426950408889634f

#if __has_builtin(__builtin_amdgcn_exp2f)
#define EXP2F(x) __builtin_amdgcn_exp2f(x)
#else
#define EXP2F(x) __expf((x) * 0.6931471805599453f)
#endif

typedef _Float16 f16x8 __attribute__((ext_vector_type(8)));
typedef _Float16 f16x4 __attribute__((ext_vector_type(4)));
typedef float f32x4 __attribute__((ext_vector_type(4)));

#define MFMA32(a, b, c) __builtin_amdgcn_mfma_f32_16x16x32_f16(a, b, c, 0, 0, 0)
#define MFMA16(a, b, c) __builtin_amdgcn_mfma_f32_16x16x16f16(a, b, c, 0, 0, 0)

// async global->LDS, 16B per lane. LDS dest is wave-uniform base + lane*16.
__device__ __forceinline__ void glds16(const void* g, void* l) {
    __builtin_amdgcn_global_load_lds(
        (const __attribute__((address_space(1))) unsigned int*)g,
        (__attribute__((address_space(3))) unsigned int*)l, 16, 0, 0);
}

// ---------------------------------------------------------------------------
// Input conversion: x -> f16; W_qkv, W_out -> transposed f16 (Bt[n][k]).
// ---------------------------------------------------------------------------
#define XV (BATCH * NTOK * INNER / 4)        // 2097152 float4 groups
#define WQ (INNER * QKV_COLS)                // 786432
#define WO (INNER * INNER)                   // 262144

__global__ __launch_bounds__(256)
void convert_inputs(const float* __restrict__ x, const float* __restrict__ Wq,
                    const float* __restrict__ Wo, _Float16* __restrict__ x_h,
                    _Float16* __restrict__ Wq_t, _Float16* __restrict__ Wo_t) {
    int idx = blockIdx.x * 256 + threadIdx.x;
    if (idx < XV) {
        float4 v = ((const float4*)x)[idx];
        f16x4 h;
        h[0] = (_Float16)v.x; h[1] = (_Float16)v.y;
        h[2] = (_Float16)v.z; h[3] = (_Float16)v.w;
        *(f16x4*)(x_h + (size_t)idx * 4) = h;
    } else if (idx < XV + WQ) {
        int i = idx - XV;
        int n = i >> 9, k = i & 511;                 // Wq_t[n][k] = Wq[k][n]
        Wq_t[i] = (_Float16)Wq[k * QKV_COLS + n];
    } else if (idx < XV + WQ + WO) {
        int i = idx - XV - WQ;
        int n = i >> 9, k = i & 511;
        Wo_t[i] = (_Float16)Wo[k * INNER + n];
    }
}

// ---------------------------------------------------------------------------
// f16 MFMA GEMM (m97 structure): C[M,N] = A[M,K] @ Bt[N,K]^T  (+bias).
// ---------------------------------------------------------------------------
template<bool OUT_F16, bool ADD_BIAS>
__global__ __launch_bounds__(256)
void gemm_f16(const _Float16* __restrict__ A, const _Float16* __restrict__ Bt,
              const float* __restrict__ bias, void* __restrict__ Cout,
              int M, int N, int K) {
    __shared__ _Float16 As[128 * 32];
    __shared__ _Float16 Bs[128 * 32];

    const int t    = threadIdx.x;
    const int l    = t & 63;
    const int w    = t >> 6;
    const int wm   = w >> 1;
    const int wn   = w & 1;
    const int quad = l >> 4;
    const int lrow = l & 15;
    const size_t row0 = (size_t)blockIdx.y * 128;
    const size_t col0 = (size_t)blockIdx.x * 128;

    const int srow = t >> 2;
    const int sch  = t & 3;

    f32x4 acc[4][4] = {};

    for (int k0 = 0; k0 < K; k0 += 32) {
        __syncthreads();
        glds16(A + (row0 + srow) * K + k0 + sch * 8,            (char*)As + t * 16);
        glds16(A + (row0 + 64 + srow) * K + k0 + sch * 8,       (char*)As + 4096 + t * 16);
        glds16(Bt + (col0 + srow) * K + k0 + sch * 8,           (char*)Bs + t * 16);
        glds16(Bt + (col0 + 64 + srow) * K + k0 + sch * 8,      (char*)Bs + 4096 + t * 16);
        __syncthreads();

        f16x8 af[4], bf[4];
#pragma unroll
        for (int i = 0; i < 4; ++i)
            af[i] = *(const f16x8*)(As + (wm * 64 + i * 16 + lrow) * 32 + quad * 8);
#pragma unroll
        for (int j = 0; j < 4; ++j)
            bf[j] = *(const f16x8*)(Bs + (wn * 64 + j * 16 + lrow) * 32 + quad * 8);
#pragma unroll
        for (int i = 0; i < 4; ++i)
#pragma unroll
            for (int j = 0; j < 4; ++j)
                acc[i][j] = __builtin_amdgcn_mfma_f32_16x16x32_f16(af[i], bf[j], acc[i][j], 0, 0, 0);
    }

#pragma unroll
    for (int i = 0; i < 4; ++i) {
#pragma unroll
        for (int j = 0; j < 4; ++j) {
            size_t r = row0 + wm * 64 + i * 16 + quad * 4;
            size_t c = col0 + wn * 64 + j * 16 + lrow;
#pragma unroll
            for (int reg = 0; reg < 4; ++reg) {
                float v = acc[i][j][reg];
                if (OUT_F16) {
                    ((_Float16*)Cout)[(r + reg) * N + c] = (_Float16)v;
                } else {
                    if (ADD_BIAS) v += bias[c];
                    ((float*)Cout)[(r + reg) * N + c] = v;
                }
            }
        }
    }
}

// ---------------------------------------------------------------------------
// V pre-transpose: vt[b][h][d][n] = qkv[b*N+n][2*INNER + h*64 + d].
// ---------------------------------------------------------------------------
__global__ __launch_bounds__(256)
void transpose_v(const _Float16* __restrict__ qkv, _Float16* __restrict__ vt) {
    __shared__ _Float16 T[64][72];
    const int t  = threadIdx.x;
    const int j0 = blockIdx.x * 64;
    const int h  = blockIdx.y, bb = blockIdx.z;
    const int jr = t >> 2;
    const int dc = (t & 3) * 16;
    const _Float16* src = qkv + ((size_t)bb * NTOK + j0 + jr) * QKV_COLS + 2 * INNER + h * DHEAD + dc;
    f16x8 v0 = *(const f16x8*)src;
    f16x8 v1 = *(const f16x8*)(src + 8);
#pragma unroll
    for (int e = 0; e < 8; ++e) { T[jr][dc + e] = v0[e]; T[jr][dc + 8 + e] = v1[e]; }
    __syncthreads();
    const int dr = t >> 2;
    const int jc = (t & 3) * 16;
    f16x8 o0, o1;
#pragma unroll
    for (int e = 0; e < 8; ++e) { o0[e] = T[jc + e][dr]; o1[e] = T[jc + 8 + e][dr]; }
    _Float16* dst = vt + (((size_t)bb * HEADS + h) * 64 + dr) * NTOK + j0 + jc;
    *(f16x8*)dst = o0;
    *(f16x8*)(dst + 8) = o1;
}

// ---------------------------------------------------------------------------
// Flash attention v5: transposed-score structure.
//   S^T tile = mfma_16x16x32(K_frag, Q_frag)  -> lane holds P^T[j=quad*4+r][m=lane&15]
//   which is exactly the B-layout (k=quad*4+e) of v_mfma_f32_16x16x16f16, so
//   PV feeds the exp2'd probabilities STRAIGHT from registers:
//   no Ps LDS buffer, no scalar ds_write_u16 transpose round-trip.
// LDS: Ks 16K + Vs 16K + biasH(f16) 7.75K = 39.75K -> 4 blocks/CU (16 waves),
// vs v4's 64K -> 2 blocks. Grid = 1024 blocks = exactly 4/CU resident.
// V fragments: ds_read_b64 of 4 consecutive j from the chunk-XOR swizzled Vs.
// ---------------------------------------------------------------------------
__global__ __launch_bounds__(256, 4)
void attn_f16_v5(const _Float16* __restrict__ qkv, const _Float16* __restrict__ vt,
                 const float* __restrict__ rel_table, _Float16* __restrict__ out) {
    __shared__ _Float16 Ks[2][64 * 64];   // [j][d], swizzled 16B chunks
    __shared__ _Float16 Vs[2][64 * 64];   // [d][j], swizzled 16B chunks
    __shared__ _Float16 biasH[3969];      // this head's bias column * log2e, f16

    const int t    = threadIdx.x;
    const int l    = t & 63;
    const int w    = t >> 6;
    const int quad = l >> 4;
    const int lrow = l & 15;
    const int h    = blockIdx.y;
    const int bb   = blockIdx.z;
    const int qr0  = blockIdx.x * 128 + w * 32;   // this wave's 32 query rows

    for (int idx = t; idx < 3969; idx += 256)
        biasH[idx] = (_Float16)(rel_table[idx * HEADS + h] * LOG2E);

    const size_t tokbase = (size_t)bb * NTOK;

    // Q fragments: Q[qr0 + mt*16 + lane&15][ksi*32 + quad*8 + e].
    // A-layout == B-layout for 16x16x32, so these serve directly as the
    // B operand of the swapped (transposed-score) QK^T.
    f16x8 aq[2][2];
#pragma unroll
    for (int mt = 0; mt < 2; ++mt)
#pragma unroll
        for (int ksi = 0; ksi < 2; ++ksi)
            aq[mt][ksi] = *(const f16x8*)(qkv + (tokbase + qr0 + mt * 16 + lrow) * QKV_COLS
                                          + h * DHEAD + ksi * 32 + quad * 8);

    // O^T accumulators: O[mt][dn] lane holds out[m=lane&15][d=dn*16+quad*4+reg]
    f32x4 O[2][4] = {};
    float l0 = 0.f, l1 = 0.f;

    // bias idx = (iy - jy + 31)*63 + 31 - jx + ix
    //   i = qr0 + mt*16 + lrow  (qr0 32-aligned => iy = qr0>>5 wave-const,
    //                            ix = mt*16 + lrow lane-const per mt)
    //   j = jt*64 + jn*16 + quad*4 + reg => jy = jt*2 + (jn>>1),
    //                                       jx = (jn&1)*16 + quad*4 + reg
    const int bconst = ((qr0 >> 5) + 31) * 63 + 31 + lrow - quad * 4;

    const int kr  = t >> 3;     // staging row 0..31
    const int ksl = t & 7;      // LDS chunk slot; holds global chunk ksl^(row&7)
    const _Float16* kbase = qkv + tokbase * QKV_COLS + INNER + h * DHEAD;
    const _Float16* vbase = vt + ((size_t)(bb * HEADS + h) * 64) * NTOK;

    auto stage = [&](int jt, int bufi) {
        const int j0s = jt * 64;
        const int swz = (ksl ^ (kr & 7)) * 8;
        glds16(kbase + (size_t)(j0s + kr) * QKV_COLS + swz,      (char*)Ks[bufi] + t * 16);
        glds16(kbase + (size_t)(j0s + 32 + kr) * QKV_COLS + swz, (char*)Ks[bufi] + 4096 + t * 16);
        glds16(vbase + (size_t)kr * NTOK + j0s + swz,            (char*)Vs[bufi] + t * 16);
        glds16(vbase + (size_t)(32 + kr) * NTOK + j0s + swz,     (char*)Vs[bufi] + 4096 + t * 16);
    };

    stage(0, 0);

    for (int jt = 0; jt < 16; ++jt) {
        const int buf = jt & 1;
        __syncthreads();                 // staged tile jt ready; prev compute done
        if (jt < 15) stage(jt + 1, buf ^ 1);

#pragma unroll
        for (int jn = 0; jn < 4; ++jn) {
            // --- S^T = (K Q^T): K as A[j][d], Q as B[d][m] ---
            const int row = jn * 16 + lrow;     // key row j for this lane
            f32x4 S0 = {}, S1 = {};
#pragma unroll
            for (int ksi = 0; ksi < 2; ++ksi) {
                f16x8 bk = *(const f16x8*)(Ks[buf] + row * 64 + (((ksi * 4 + quad) ^ (row & 7)) * 8));
                S0 = MFMA32(bk, aq[0][ksi], S0);   // S^T[j=quad*4+reg][m=lane&15]
                S1 = MFMA32(bk, aq[1][ksi], S1);
            }

            // --- p = exp2(s*scale' + bias'); pack to PV B-fragment in-register ---
            const int base0 = bconst - (jt * 2 + (jn >> 1)) * 63 - (jn & 1) * 16;
            f16x4 pb0, pb1;
            {
                float p0 = EXP2F(fmaf(S0[0], SCALE_L2E, (float)biasH[base0 - 0]));
                float p1 = EXP2F(fmaf(S0[1], SCALE_L2E, (float)biasH[base0 - 1]));
                float p2 = EXP2F(fmaf(S0[2], SCALE_L2E, (float)biasH[base0 - 2]));
                float p3 = EXP2F(fmaf(S0[3], SCALE_L2E, (float)biasH[base0 - 3]));
                l0 += (p0 + p1) + (p2 + p3);
                pb0[0] = (_Float16)p0; pb0[1] = (_Float16)p1;
                pb0[2] = (_Float16)p2; pb0[3] = (_Float16)p3;
            }
            {
                const int base1 = base0 + 16;
                float p0 = EXP2F(fmaf(S1[0], SCALE_L2E, (float)biasH[base1 - 0]));
                float p1 = EXP2F(fmaf(S1[1], SCALE_L2E, (float)biasH[base1 - 1]));
                float p2 = EXP2F(fmaf(S1[2], SCALE_L2E, (float)biasH[base1 - 2]));
                float p3 = EXP2F(fmaf(S1[3], SCALE_L2E, (float)biasH[base1 - 3]));
                l1 += (p0 + p1) + (p2 + p3);
                pb1[0] = (_Float16)p0; pb1[1] = (_Float16)p1;
                pb1[2] = (_Float16)p2; pb1[3] = (_Float16)p3;
            }

            // --- O^T += V^T P^T : V as A[d][j'] (b64 of 4 consecutive j),
            //     packed p as B[j'][m], K=16 MFMA ---
#pragma unroll
            for (int dn = 0; dn < 4; ++dn) {
                const int d = dn * 16 + lrow;
                f16x4 av = *(const f16x4*)(Vs[buf] + d * 64
                              + (((jn * 2 + (quad >> 1)) ^ (d & 7)) * 8) + (quad & 1) * 4);
                O[0][dn] = MFMA16(av, pb0, O[0][dn]);
                O[1][dn] = MFMA16(av, pb1, O[1][dn]);
            }
        }
    }

    // --- l reduction: lanes {m, m+16, m+32, m+48} hold quad-partials of row m ---
#pragma unroll
    for (int mt = 0; mt < 2; ++mt) {
        float s = mt ? l1 : l0;
        s += __shfl_xor(s, 16);
        s += __shfl_xor(s, 32);
        const float inv = 1.f / s;
        const size_t orow = (tokbase + qr0 + mt * 16 + lrow) * INNER + h * DHEAD;
#pragma unroll
        for (int dn = 0; dn < 4; ++dn) {
            const f32x4 o = O[mt][dn];
            f16x4 ov;
            ov[0] = (_Float16)(o[0] * inv); ov[1] = (_Float16)(o[1] * inv);
            ov[2] = (_Float16)(o[2] * inv); ov[3] = (_Float16)(o[3] * inv);
            *(f16x4*)(out + orow + dn * 16 + quad * 4) = ov;
        }
    }
}

// ---------------------------------------------------------------------------
extern "C" void kernel_launch(void* const* d_in, const int* in_sizes, int n_in,
                              void* d_out, int out_size, void* d_ws, size_t ws_size,
                              hipStream_t stream) {
    const float* x         = (const float*)d_in[0];
    const float* W_qkv     = (const float*)d_in[1];
    const float* rel_table = (const float*)d_in[2];
    const float* W_out     = (const float*)d_in[3];
    const float* b_out     = (const float*)d_in[4];

    _Float16* x_h   = (_Float16*)d_ws;                        // 8,388,608
    _Float16* Wq_t  = x_h + (size_t)BATCH * NTOK * INNER;     // 786,432
    _Float16* Wo_t  = Wq_t + (size_t)INNER * QKV_COLS;        // 262,144
    _Float16* qkv_h = Wo_t + (size_t)INNER * INNER;           // 25,165,824
    _Float16* att_h = qkv_h + (size_t)BATCH * NTOK * QKV_COLS;// 8,388,608
    _Float16* vt_g  = att_h + (size_t)BATCH * NTOK * INNER;   // 8,388,608

    const int M = BATCH * NTOK;  // 16384

    convert_inputs<<<(XV + WQ + WO + 255) / 256, 256, 0, stream>>>(
        x, W_qkv, W_out, x_h, Wq_t, Wo_t);

    gemm_f16<true, false><<<dim3(QKV_COLS / 128, M / 128), 256, 0, stream>>>(
        x_h, Wq_t, nullptr, qkv_h, M, QKV_COLS, INNER);

    transpose_v<<<dim3(NTOK / 64, HEADS, BATCH), 256, 0, stream>>>(qkv_h, vt_g);

    attn_f16_v5<<<dim3(NTOK / 128, HEADS, BATCH), 256, 0, stream>>>(
        qkv_h, vt_g, rel_table, att_h);

    gemm_f16<false, true><<<dim3(INNER / 128, M / 128), 256, 0, stream>>>(
        att_h, Wo_t, b_out, d_out, M, INNER, INNER);
}

// Round 3
// 214.248 us; speedup vs baseline: 1.1381x; 1.1368x over previous
//
#include <hip/hip_runtime.h>
#include <math.h>

#define BATCH 16
#define NTOK 1024
#define HEADS 8
#define DHEAD 64
#define INNER 512
#define QKV_COLS 1536
// 0.125 * log2(e): p = exp2(qk*SCALE_L2E + bias*log2e)
#define SCALE_L2E 0.1803368801111244f
#define LOG2E 1.4426950408889634f

#if __has_builtin(__builtin_amdgcn_exp2f)
#define EXP2F(x) __builtin_amdgcn_exp2f(x)
#else
#define EXP2F(x) __expf((x) * 0.6931471805599453f)
#endif

typedef _Float16 f16x8 __attribute__((ext_vector_type(8)));
typedef _Float16 f16x4 __attribute__((ext_vector_type(4)));
typedef float f32x4 __attribute__((ext_vector_type(4)));

#define MFMA32(a, b, c) __builtin_amdgcn_mfma_f32_16x16x32_f16(a, b, c, 0, 0, 0)

// async global->LDS, 16B per lane. LDS dest is wave-uniform base + lane*16.
__device__ __forceinline__ void glds16(const void* g, void* l) {
    __builtin_amdgcn_global_load_lds(
        (const __attribute__((address_space(1))) unsigned int*)g,
        (__attribute__((address_space(3))) unsigned int*)l, 16, 0, 0);
}

// ---------------------------------------------------------------------------
// Input conversion: x -> f16; W_qkv, W_out -> transposed f16 (Bt[n][k]).
// ---------------------------------------------------------------------------
#define XV (BATCH * NTOK * INNER / 4)        // 2097152 float4 groups
#define WQ (INNER * QKV_COLS)                // 786432
#define WO (INNER * INNER)                   // 262144

__global__ __launch_bounds__(256)
void convert_inputs(const float* __restrict__ x, const float* __restrict__ Wq,
                    const float* __restrict__ Wo, _Float16* __restrict__ x_h,
                    _Float16* __restrict__ Wq_t, _Float16* __restrict__ Wo_t) {
    int idx = blockIdx.x * 256 + threadIdx.x;
    if (idx < XV) {
        float4 v = ((const float4*)x)[idx];
        f16x4 h;
        h[0] = (_Float16)v.x; h[1] = (_Float16)v.y;
        h[2] = (_Float16)v.z; h[3] = (_Float16)v.w;
        *(f16x4*)(x_h + (size_t)idx * 4) = h;
    } else if (idx < XV + WQ) {
        int i = idx - XV;
        int n = i >> 9, k = i & 511;                 // Wq_t[n][k] = Wq[k][n]
        Wq_t[i] = (_Float16)Wq[k * QKV_COLS + n];
    } else if (idx < XV + WQ + WO) {
        int i = idx - XV - WQ;
        int n = i >> 9, k = i & 511;
        Wo_t[i] = (_Float16)Wo[k * INNER + n];
    }
}

// ---------------------------------------------------------------------------
// f16 MFMA GEMM (m97 structure): C[M,N] = A[M,K] @ Bt[N,K]^T  (+bias).
// ---------------------------------------------------------------------------
template<bool OUT_F16, bool ADD_BIAS>
__global__ __launch_bounds__(256)
void gemm_f16(const _Float16* __restrict__ A, const _Float16* __restrict__ Bt,
              const float* __restrict__ bias, void* __restrict__ Cout,
              int M, int N, int K) {
    __shared__ _Float16 As[128 * 32];
    __shared__ _Float16 Bs[128 * 32];

    const int t    = threadIdx.x;
    const int l    = t & 63;
    const int w    = t >> 6;
    const int wm   = w >> 1;
    const int wn   = w & 1;
    const int quad = l >> 4;
    const int lrow = l & 15;
    const size_t row0 = (size_t)blockIdx.y * 128;
    const size_t col0 = (size_t)blockIdx.x * 128;

    const int srow = t >> 2;
    const int sch  = t & 3;

    f32x4 acc[4][4] = {};

    for (int k0 = 0; k0 < K; k0 += 32) {
        __syncthreads();
        glds16(A + (row0 + srow) * K + k0 + sch * 8,            (char*)As + t * 16);
        glds16(A + (row0 + 64 + srow) * K + k0 + sch * 8,       (char*)As + 4096 + t * 16);
        glds16(Bt + (col0 + srow) * K + k0 + sch * 8,           (char*)Bs + t * 16);
        glds16(Bt + (col0 + 64 + srow) * K + k0 + sch * 8,      (char*)Bs + 4096 + t * 16);
        __syncthreads();

        f16x8 af[4], bf[4];
#pragma unroll
        for (int i = 0; i < 4; ++i)
            af[i] = *(const f16x8*)(As + (wm * 64 + i * 16 + lrow) * 32 + quad * 8);
#pragma unroll
        for (int j = 0; j < 4; ++j)
            bf[j] = *(const f16x8*)(Bs + (wn * 64 + j * 16 + lrow) * 32 + quad * 8);
#pragma unroll
        for (int i = 0; i < 4; ++i)
#pragma unroll
            for (int j = 0; j < 4; ++j)
                acc[i][j] = __builtin_amdgcn_mfma_f32_16x16x32_f16(af[i], bf[j], acc[i][j], 0, 0, 0);
    }

#pragma unroll
    for (int i = 0; i < 4; ++i) {
#pragma unroll
        for (int j = 0; j < 4; ++j) {
            size_t r = row0 + wm * 64 + i * 16 + quad * 4;
            size_t c = col0 + wn * 64 + j * 16 + lrow;
#pragma unroll
            for (int reg = 0; reg < 4; ++reg) {
                float v = acc[i][j][reg];
                if (OUT_F16) {
                    ((_Float16*)Cout)[(r + reg) * N + c] = (_Float16)v;
                } else {
                    if (ADD_BIAS) v += bias[c];
                    ((float*)Cout)[(r + reg) * N + c] = v;
                }
            }
        }
    }
}

// ---------------------------------------------------------------------------
// V pre-transpose: vt[b][h][d][n] = qkv[b*N+n][2*INNER + h*64 + d].
// ---------------------------------------------------------------------------
__global__ __launch_bounds__(256)
void transpose_v(const _Float16* __restrict__ qkv, _Float16* __restrict__ vt) {
    __shared__ _Float16 T[64][72];
    const int t  = threadIdx.x;
    const int j0 = blockIdx.x * 64;
    const int h  = blockIdx.y, bb = blockIdx.z;
    const int jr = t >> 2;
    const int dc = (t & 3) * 16;
    const _Float16* src = qkv + ((size_t)bb * NTOK + j0 + jr) * QKV_COLS + 2 * INNER + h * DHEAD + dc;
    f16x8 v0 = *(const f16x8*)src;
    f16x8 v1 = *(const f16x8*)(src + 8);
#pragma unroll
    for (int e = 0; e < 8; ++e) { T[jr][dc + e] = v0[e]; T[jr][dc + 8 + e] = v1[e]; }
    __syncthreads();
    const int dr = t >> 2;
    const int jc = (t & 3) * 16;
    f16x8 o0, o1;
#pragma unroll
    for (int e = 0; e < 8; ++e) { o0[e] = T[jc + e][dr]; o1[e] = T[jc + 8 + e][dr]; }
    _Float16* dst = vt + (((size_t)bb * HEADS + h) * 64 + dr) * NTOK + j0 + jc;
    *(f16x8*)dst = o0;
    *(f16x8*)(dst + 8) = o1;
}

// ---------------------------------------------------------------------------
// Flash attention v6: transposed-score + permuted-key PV on full-rate MFMA32.
// v5 post-mortem fixes:
//  (1) 16x16x16 MFMA measured half-rate (same ~4.8cy as K=32) -> PV now uses
//      16x16x32. Enabled by loading K rows PERMUTED so S^T row r <-> key
//      8*(r>>2)+(r&3)+4s: lane(quad) then holds P for keys quad*8..quad*8+7 =
//      exactly the K=32 B-fragment. V stays in natural column order.
//  (2) f16 bias reads were 4-way bank conflicts (4.19M cycles) -> bias back
//      to f32 (31-word span = 31 banks = free; ds_read2_b32 pairing).
//  (3) f32 bias costs 15.9K -> 512-thread blocks (8 waves share one K/V tile):
//      LDS 47.5K/block, grid 512 = exactly 2 blocks/CU co-resident (16 waves),
//      staging halved to 2 glds16/thread/jt, no 3+1 tail round.
// Ks swizzle fK(row)=(row&3)|(((row>>3)&1)<<2) used identically on stage and
// read (correct by construction); gives 8 lanes/slot = v4-proven free pattern.
// ---------------------------------------------------------------------------
__global__ __launch_bounds__(512, 4)
void attn_f16_v6(const _Float16* __restrict__ qkv, const _Float16* __restrict__ vt,
                 const float* __restrict__ rel_table, _Float16* __restrict__ out) {
    __shared__ _Float16 Ks[2][64 * 64];   // [key][d], fK-swizzled 16B chunks
    __shared__ _Float16 Vs[2][64 * 64];   // [d][j], (row&7)-swizzled 16B chunks
    __shared__ float biasS[3969];         // this head's bias column * log2e

    const int t    = threadIdx.x;
    const int l    = t & 63;
    const int w    = t >> 6;              // 0..7
    const int quad = l >> 4;
    const int lrow = l & 15;
    const int h    = blockIdx.y;
    const int bb   = blockIdx.z;
    const int qr0  = blockIdx.x * 256 + w * 32;   // this wave's 32 query rows

    for (int idx = t; idx < 3969; idx += 512)
        biasS[idx] = rel_table[idx * HEADS + h] * LOG2E;

    const size_t tokbase = (size_t)bb * NTOK;

    // Q fragments: Q[qr0 + mt*16 + lrow][ksi*32 + quad*8 + e].
    // A-layout == B-layout for 16x16x32 -> used directly as B of swapped QK^T.
    f16x8 aq[2][2];
#pragma unroll
    for (int mt = 0; mt < 2; ++mt)
#pragma unroll
        for (int ksi = 0; ksi < 2; ++ksi)
            aq[mt][ksi] = *(const f16x8*)(qkv + (tokbase + qr0 + mt * 16 + lrow) * QKV_COLS
                                          + h * DHEAD + ksi * 32 + quad * 8);

    // O^T accumulators: O[mt][dn] lane holds out[m=lrow][d=dn*16+quad*4+reg]
    f32x4 O[2][4] = {};
    float l0 = 0.f, l1 = 0.f;

    const int iy = qr0 >> 5;                               // wave-constant
    // A-row lrow reads key krow_base(+4s +32jn0); fK of that key is lane-const:
    const int krow_base = 8 * (lrow >> 2) + (lrow & 3);
    const int fKl = (lrow & 3) + 4 * ((lrow >> 2) & 1);

    const int kr  = t >> 3;     // staging row 0..63
    const int ksl = t & 7;      // LDS chunk slot
    const int fKr = (kr & 3) + 4 * ((kr >> 3) & 1);
    const _Float16* kbase = qkv + tokbase * QKV_COLS + INNER + h * DHEAD;
    const _Float16* vbase = vt + ((size_t)(bb * HEADS + h) * 64) * NTOK;

    auto stage = [&](int jt, int bufi) {
        const int j0s = jt * 64;
        glds16(kbase + (size_t)(j0s + kr) * QKV_COLS + (ksl ^ fKr) * 8, (char*)Ks[bufi] + t * 16);
        glds16(vbase + (size_t)kr * NTOK + j0s + (ksl ^ (kr & 7)) * 8,  (char*)Vs[bufi] + t * 16);
    };

    stage(0, 0);

    for (int jt = 0; jt < 16; ++jt) {
        const int buf = jt & 1;
        __syncthreads();                 // staged tile jt ready; prev compute done
        if (jt < 15) stage(jt + 1, buf ^ 1);

#pragma unroll
        for (int jn0 = 0; jn0 < 2; ++jn0) {
            f16x8 pb0, pb1;              // PV B-fragments (built across s=0,1)
#pragma unroll
            for (int s = 0; s < 2; ++s) {
                // --- S^T = K Q^T on permuted K rows ---
                const int krow = jn0 * 32 + krow_base + 4 * s;
                f32x4 S0 = {}, S1 = {};
#pragma unroll
                for (int ksi = 0; ksi < 2; ++ksi) {
                    f16x8 bk = *(const f16x8*)(Ks[buf] + krow * 64
                                               + (((ksi * 4 + quad) ^ fKl) * 8));
                    S0 = MFMA32(bk, aq[0][ksi], S0);   // P^T for keys 8q+4s+reg
                    S1 = MFMA32(bk, aq[1][ksi], S1);
                }
                // bias idx = (iy-jy+31)*63 + 31 + ix - jx
                //   jy = 2jt+jn0 (uniform), jx = 8*quad + 4*s + reg,
                //   ix = mt*16 + lrow
                const int base = (iy - (jt * 2 + jn0) + 31) * 63 + 31 + lrow
                                 - 8 * quad - 4 * s;
                {   // mt = 0
                    float p0 = EXP2F(fmaf(S0[0], SCALE_L2E, biasS[base - 0]));
                    float p1 = EXP2F(fmaf(S0[1], SCALE_L2E, biasS[base - 1]));
                    float p2 = EXP2F(fmaf(S0[2], SCALE_L2E, biasS[base - 2]));
                    float p3 = EXP2F(fmaf(S0[3], SCALE_L2E, biasS[base - 3]));
                    l0 += (p0 + p1) + (p2 + p3);
                    pb0[s * 4 + 0] = (_Float16)p0; pb0[s * 4 + 1] = (_Float16)p1;
                    pb0[s * 4 + 2] = (_Float16)p2; pb0[s * 4 + 3] = (_Float16)p3;
                }
                {   // mt = 1
                    const int b1 = base + 16;
                    float p0 = EXP2F(fmaf(S1[0], SCALE_L2E, biasS[b1 - 0]));
                    float p1 = EXP2F(fmaf(S1[1], SCALE_L2E, biasS[b1 - 1]));
                    float p2 = EXP2F(fmaf(S1[2], SCALE_L2E, biasS[b1 - 2]));
                    float p3 = EXP2F(fmaf(S1[3], SCALE_L2E, biasS[b1 - 3]));
                    l1 += (p0 + p1) + (p2 + p3);
                    pb1[s * 4 + 0] = (_Float16)p0; pb1[s * 4 + 1] = (_Float16)p1;
                    pb1[s * 4 + 2] = (_Float16)p2; pb1[s * 4 + 3] = (_Float16)p3;
                }
            }

            // --- O^T += V^T P^T : K=32 MFMA, V rows d, keys jn0*32+quad*8+e ---
#pragma unroll
            for (int dn = 0; dn < 4; ++dn) {
                const int d = dn * 16 + lrow;
                f16x8 av = *(const f16x8*)(Vs[buf] + d * 64
                              + (((jn0 * 4 + quad) ^ (d & 7)) * 8));
                O[0][dn] = MFMA32(av, pb0, O[0][dn]);
                O[1][dn] = MFMA32(av, pb1, O[1][dn]);
            }
        }
    }

    // --- l reduction: lanes {m, m+16, m+32, m+48} hold quad-partials of row m ---
#pragma unroll
    for (int mt = 0; mt < 2; ++mt) {
        float s = mt ? l1 : l0;
        s += __shfl_xor(s, 16);
        s += __shfl_xor(s, 32);
        const float inv = 1.f / s;
        const size_t orow = (tokbase + qr0 + mt * 16 + lrow) * INNER + h * DHEAD;
#pragma unroll
        for (int dn = 0; dn < 4; ++dn) {
            const f32x4 o = O[mt][dn];
            f16x4 ov;
            ov[0] = (_Float16)(o[0] * inv); ov[1] = (_Float16)(o[1] * inv);
            ov[2] = (_Float16)(o[2] * inv); ov[3] = (_Float16)(o[3] * inv);
            *(f16x4*)(out + orow + dn * 16 + quad * 4) = ov;
        }
    }
}

// ---------------------------------------------------------------------------
extern "C" void kernel_launch(void* const* d_in, const int* in_sizes, int n_in,
                              void* d_out, int out_size, void* d_ws, size_t ws_size,
                              hipStream_t stream) {
    const float* x         = (const float*)d_in[0];
    const float* W_qkv     = (const float*)d_in[1];
    const float* rel_table = (const float*)d_in[2];
    const float* W_out     = (const float*)d_in[3];
    const float* b_out     = (const float*)d_in[4];

    _Float16* x_h   = (_Float16*)d_ws;                        // 8,388,608
    _Float16* Wq_t  = x_h + (size_t)BATCH * NTOK * INNER;     // 786,432
    _Float16* Wo_t  = Wq_t + (size_t)INNER * QKV_COLS;        // 262,144
    _Float16* qkv_h = Wo_t + (size_t)INNER * INNER;           // 25,165,824
    _Float16* att_h = qkv_h + (size_t)BATCH * NTOK * QKV_COLS;// 8,388,608
    _Float16* vt_g  = att_h + (size_t)BATCH * NTOK * INNER;   // 8,388,608

    const int M = BATCH * NTOK;  // 16384

    convert_inputs<<<(XV + WQ + WO + 255) / 256, 256, 0, stream>>>(
        x, W_qkv, W_out, x_h, Wq_t, Wo_t);

    gemm_f16<true, false><<<dim3(QKV_COLS / 128, M / 128), 256, 0, stream>>>(
        x_h, Wq_t, nullptr, qkv_h, M, QKV_COLS, INNER);

    transpose_v<<<dim3(NTOK / 64, HEADS, BATCH), 256, 0, stream>>>(qkv_h, vt_g);

    attn_f16_v6<<<dim3(NTOK / 256, HEADS, BATCH), 512, 0, stream>>>(
        qkv_h, vt_g, rel_table, att_h);

    gemm_f16<false, true><<<dim3(INNER / 128, M / 128), 256, 0, stream>>>(
        att_h, Wo_t, b_out, d_out, M, INNER, INNER);
}